// Round 21
// baseline (448.172 us; speedup 1.0000x reference)
//
#include <hip/hip_runtime.h>

#define TT 7
#define DD 40
#define HH 64
#define RB 128         // rows per block (16 per wave)
#define NTH 512        // 8 autonomous waves; NO main-loop barriers
#define L2E 1.44269504088896340736f

typedef _Float16 f16x8 __attribute__((ext_vector_type(8)));
typedef float f32x4 __attribute__((ext_vector_type(4)));

#define MFMA(acc, a, b) acc = __builtin_amdgcn_mfma_f32_16x16x32_f16(a, b, acc, 0, 0, 0)
// weight B-fragment in LDS: lane l's 16B at block*1024 + l*16
#define BFRAG(L, K, G, Q) \
  (*(const f16x8*)&s_wb[(((((L) * 4 + (K)) * 4 + (G)) * 4 + (Q)) << 9) + lx8])

__device__ __forceinline__ float fast_rcp(float x) { return __builtin_amdgcn_rcpf(x); }
__device__ __forceinline__ float ex2(float x) { return __builtin_amdgcn_exp2f(x); }

// Fused LSTM cell: 5 ex2 + 3 rcp. Gates pre-scaled by log2e (gate2 & c-path by 2*log2e).
__device__ __forceinline__ float lstm_hc(float a0, float a1, float a2, float a3,
                                         float &c) {
  float A = ex2(-a0);
  float E = ex2(a2);
  float F = ex2(-a1);
  float O = ex2(-a3);
  float igg = (E - 1.f) * fast_rcp((1.f + A) * (1.f + E));   // i * g
  float fg  = fast_rcp(1.f + F);                             // f
  c = fg * c + igg;
  float C = ex2(c * (2.f * L2E));
  return (C - 1.f) * fast_rcp((1.f + O) * (1.f + C));        // o * tanh(c)
}

__device__ __forceinline__ f16x8 zf() {
  f16x8 r;
  #pragma unroll
  for (int i = 0; i < 8; ++i) r[i] = (_Float16)0.f;
  return r;
}
__device__ __forceinline__ f16x8 cvt8s(const float* p, float s) {
  float4 a = *(const float4*)p, b = *(const float4*)(p + 4);
  f16x8 r;
  r[0] = (_Float16)(a.x * s); r[1] = (_Float16)(a.y * s);
  r[2] = (_Float16)(a.z * s); r[3] = (_Float16)(a.w * s);
  r[4] = (_Float16)(b.x * s); r[5] = (_Float16)(b.y * s);
  r[6] = (_Float16)(b.z * s); r[7] = (_Float16)(b.w * s);
  return r;
}
__device__ __forceinline__ f16x8 cvt8(const float* p) {
  float4 a = *(const float4*)p, b = *(const float4*)(p + 4);
  f16x8 r;
  r[0] = (_Float16)a.x; r[1] = (_Float16)a.y; r[2] = (_Float16)a.z; r[3] = (_Float16)a.w;
  r[4] = (_Float16)b.x; r[5] = (_Float16)b.y; r[6] = (_Float16)b.z; r[7] = (_Float16)b.w;
  return r;
}
__device__ __forceinline__ f16x8 pk8(float4 a, float4 b) {
  f16x8 r;
  auto p0 = __builtin_amdgcn_cvt_pkrtz(a.x, a.y);
  auto p1 = __builtin_amdgcn_cvt_pkrtz(a.z, a.w);
  auto p2 = __builtin_amdgcn_cvt_pkrtz(b.x, b.y);
  auto p3 = __builtin_amdgcn_cvt_pkrtz(b.z, b.w);
  r[0] = p0[0]; r[1] = p0[1]; r[2] = p1[0]; r[3] = p1[1];
  r[4] = p2[0]; r[5] = p2[1]; r[6] = p3[0]; r[7] = p3[1];
  return r;
}

__global__ __launch_bounds__(NTH, 2) void lstm2_auto_kernel(
    const float* __restrict__ x,
    const float* __restrict__ Wih0, const float* __restrict__ Whh0,
    const float* __restrict__ bih0, const float* __restrict__ bhh0,
    const float* __restrict__ Wih1, const float* __restrict__ Whh1,
    const float* __restrict__ bih1, const float* __restrict__ bhh1,
    const float* __restrict__ W1, const float* __restrict__ b1,
    const float* __restrict__ W2, const float* __restrict__ b2,
    float* __restrict__ out)
{
  // 131,072 + 18,432 = 149,504 B  (<= 160 KiB), 1 block/CU.
  // s_wb: 128 weight-fragment blocks of 1 KiB: BID = ((layer*4+kind)*4+g)*4+q
  //   kind: 0 = input k0..31, 1 = input k32.. (L0: k32-39, lg0 only; rest zero),
  //         2 = recurrent k0..31, 3 = recurrent k32..63
  __shared__ __align__(16) unsigned short s_wb[128 * 512];
  __shared__ __align__(16) unsigned short s_tr[8][16 * 72];  // per-wave transpose scratch

  const int tid = threadIdx.x;
  const int l   = tid & 63;
  const int wv  = tid >> 6;
  const int l15 = l & 15;
  const int lg  = l >> 4;
  const int lx8 = l * 8;          // u16 offset of this lane's 16B fragment slot
  const int blk = blockIdx.x;

  // ---- stage all weights as B-fragments (16 blocks per wave) ----
  for (int b = wv; b < 128; b += 8) {
    const int q = b & 3, g = (b >> 2) & 3, kd = (b >> 4) & 3, ly = b >> 6;
    const float gs = (g == 2) ? 2.f * L2E : L2E;
    const int n = g * 64 + q * 16 + l15;
    f16x8 f;
    if (ly == 0) {
      if (kd == 0)      f = cvt8s(&Wih0[n * DD + lg * 8], gs);
      else if (kd == 1) f = (lg == 0) ? cvt8s(&Wih0[n * DD + 32], gs) : zf();
      else if (kd == 2) f = cvt8s(&Whh0[n * HH + lg * 8], gs);
      else              f = cvt8s(&Whh0[n * HH + 32 + lg * 8], gs);
    } else {
      if (kd == 0)      f = cvt8s(&Wih1[n * HH + lg * 8], gs);
      else if (kd == 1) f = cvt8s(&Wih1[n * HH + 32 + lg * 8], gs);
      else if (kd == 2) f = cvt8s(&Whh1[n * HH + lg * 8], gs);
      else              f = cvt8s(&Whh1[n * HH + 32 + lg * 8], gs);
    }
    *(f16x8*)&s_wb[b * 512 + lx8] = f;
  }

  // ---- biases (per-lane, all gate/quarter combos) ----
  float b0v[4][4], b1v[4][4];
  #pragma unroll
  for (int g = 0; g < 4; ++g) {
    const float gs = (g == 2) ? 2.f * L2E : L2E;
    #pragma unroll
    for (int q = 0; q < 4; ++q) {
      int n = g * 64 + q * 16 + l15;
      b0v[g][q] = (bih0[n] + bhh0[n]) * gs;
      b1v[g][q] = (bih1[n] + bhh1[n]) * gs;
    }
  }

  // ---- x prefetch for step 0 (per-lane direct loads; L2-hot after step 0) ----
  const float* xr = x + (size_t)(blk * RB + wv * 16 + l15) * (TT * DD);
  float4 xf0 = *(const float4*)(xr + lg * 8);
  float4 xf1 = *(const float4*)(xr + lg * 8 + 4);
  float4 xf2 = *(const float4*)(xr + 32);
  float4 xf3 = *(const float4*)(xr + 36);

  float cst0[4][4], cst1[4][4];   // [quarter][r]
  #pragma unroll
  for (int q = 0; q < 4; ++q)
    #pragma unroll
    for (int r = 0; r < 4; ++r) { cst0[q][r] = 0.f; cst1[q][r] = 0.f; }

  f16x8 h1A0 = zf(), h1A1 = zf(), h2A0 = zf(), h2A1 = zf();
  unsigned short* tr = &s_tr[wv][0];

  __syncthreads();   // weights staged — the ONLY block-wide barrier

  #pragma unroll 1
  for (int s = 0; s < TT; ++s) {
    f16x8 xA0 = pk8(xf0, xf1);
    f16x8 xA1 = (lg == 0) ? pk8(xf2, xf3) : zf();
    if (s < TT - 1) {               // prefetch x[s+1]
      const float* xn = xr + (s + 1) * DD;
      xf0 = *(const float4*)(xn + lg * 8);
      xf1 = *(const float4*)(xn + lg * 8 + 4);
      xf2 = *(const float4*)(xn + 32);
      xf3 = *(const float4*)(xn + 36);
    }

    // ---- layer 0: h1[s] (rec operand h1A = h1[s-1]; zero at s=0) ----
    #pragma unroll
    for (int q = 0; q < 4; ++q) {
      f32x4 acc[4];
      #pragma unroll
      for (int g = 0; g < 4; ++g) {
        f32x4 a = (f32x4){b0v[g][q], b0v[g][q], b0v[g][q], b0v[g][q]};
        MFMA(a, xA0, BFRAG(0, 0, g, q));
        MFMA(a, xA1, BFRAG(0, 1, g, q));
        MFMA(a, h1A0, BFRAG(0, 2, g, q));
        MFMA(a, h1A1, BFRAG(0, 3, g, q));
        acc[g] = a;
      }
      #pragma unroll
      for (int r = 0; r < 4; ++r) {
        float h = lstm_hc(acc[0][r], acc[1][r], acc[2][r], acc[3][r], cst0[q][r]);
        tr[(lg * 4 + r) * 72 + q * 16 + l15] =
            __builtin_bit_cast(unsigned short, (_Float16)h);
      }
    }
    // transpose read-back (intra-wave, in-order DS — no barrier)
    h1A0 = *(const f16x8*)&tr[l15 * 72 + lg * 8];
    h1A1 = *(const f16x8*)&tr[l15 * 72 + 32 + lg * 8];

    // ---- layer 1: h2[s] (input h1[s]; rec h2A = h2[s-1], zero at s=0) ----
    #pragma unroll
    for (int q = 0; q < 4; ++q) {
      f32x4 acc[4];
      #pragma unroll
      for (int g = 0; g < 4; ++g) {
        f32x4 a = (f32x4){b1v[g][q], b1v[g][q], b1v[g][q], b1v[g][q]};
        MFMA(a, h1A0, BFRAG(1, 0, g, q));
        MFMA(a, h1A1, BFRAG(1, 1, g, q));
        MFMA(a, h2A0, BFRAG(1, 2, g, q));
        MFMA(a, h2A1, BFRAG(1, 3, g, q));
        acc[g] = a;
      }
      #pragma unroll
      for (int r = 0; r < 4; ++r) {
        float h = lstm_hc(acc[0][r], acc[1][r], acc[2][r], acc[3][r], cst1[q][r]);
        tr[(lg * 4 + r) * 72 + q * 16 + l15] =
            __builtin_bit_cast(unsigned short, (_Float16)h);
      }
    }
    h2A0 = *(const f16x8*)&tr[l15 * 72 + lg * 8];
    h2A1 = *(const f16x8*)&tr[l15 * 72 + 32 + lg * 8];
  }

  // ---- FC head (wave-local): hid = relu(h2[6] @ W1^T + b1) via MFMA ----
  {
    float* hid = (float*)tr;   // [16][36] f32 overlays scratch (h2A already in regs)
    #pragma unroll
    for (int f = 0; f < 2; ++f) {
      int n = f * 16 + l15;
      f16x8 Bf0 = cvt8(&W1[n * 64 + lg * 8]);
      f16x8 Bf1 = cvt8(&W1[n * 64 + 32 + lg * 8]);
      float bb = b1[n];
      f32x4 accf = (f32x4){bb, bb, bb, bb};
      MFMA(accf, h2A0, Bf0);
      MFMA(accf, h2A1, Bf1);
      #pragma unroll
      for (int r = 0; r < 4; ++r)
        hid[(lg * 4 + r) * 36 + f * 16 + l15] = fmaxf(accf[r], 0.f);
    }
  }
  if (l < 16) {
    const float* hid = (const float*)tr;
    float a = b2[0];
    #pragma unroll
    for (int kq = 0; kq < 8; ++kq) {
      float4 hv = *(const float4*)&hid[l * 36 + kq * 4];
      float4 wv4 = *(const float4*)&W2[kq * 4];
      a += hv.x * wv4.x + hv.y * wv4.y + hv.z * wv4.z + hv.w * wv4.w;
    }
    out[blk * RB + wv * 16 + l] = a;
  }
}

extern "C" void kernel_launch(void* const* d_in, const int* in_sizes, int n_in,
                              void* d_out, int out_size, void* d_ws, size_t ws_size,
                              hipStream_t stream) {
  const float* x    = (const float*)d_in[0];
  const float* Wih0 = (const float*)d_in[1];
  const float* Whh0 = (const float*)d_in[2];
  const float* bih0 = (const float*)d_in[3];
  const float* bhh0 = (const float*)d_in[4];
  const float* Wih1 = (const float*)d_in[5];
  const float* Whh1 = (const float*)d_in[6];
  const float* bih1 = (const float*)d_in[7];
  const float* bhh1 = (const float*)d_in[8];
  const float* W1   = (const float*)d_in[9];
  const float* b1   = (const float*)d_in[10];
  const float* W2   = (const float*)d_in[11];
  const float* b2   = (const float*)d_in[12];
  float* out = (float*)d_out;

  const int Btot = in_sizes[0] / (TT * DD);   // 32768
  dim3 grid(Btot / RB), block(NTH);           // 256 blocks = exactly 1 per CU
  lstm2_auto_kernel<<<grid, block, 0, stream>>>(
      x, Wih0, Whh0, bih0, bhh0, Wih1, Whh1, bih1, bhh1, W1, b1, W2, b2, out);
}

// Round 22
// 55.858 us; speedup vs baseline: 8.0235x; 8.0235x over previous
//
#include <hip/hip_runtime.h>

#define TT 7
#define DD 40
#define HH 64
#define RB 128         // rows per block
#define NRT 8          // row-tiles of 16 per wave (processed in pairs)
#define NTH 512        // 8 waves: 0-3 = layer 0 (j-quarters), 4-7 = layer 1
#define HS 72          // u16 stride in h planes (144 B rows -> 2-way-free b128)
#define XP 44          // float stride of x rows in LDS (11 x 16B chunks)
#define L2E 1.44269504088896340736f

typedef _Float16 f16x8 __attribute__((ext_vector_type(8)));
typedef float f32x4 __attribute__((ext_vector_type(4)));

#define MFMA(acc, a, b) acc = __builtin_amdgcn_mfma_f32_16x16x32_f16(a, b, acc, 0, 0, 0)

__device__ __forceinline__ float fast_rcp(float x) { return __builtin_amdgcn_rcpf(x); }
__device__ __forceinline__ float ex2(float x) { return __builtin_amdgcn_exp2f(x); }

// Fused LSTM cell epilogue: 5 ex2 + 3 rcp. Gates pre-scaled by log2e (gate2 & c by 2log2e).
__device__ __forceinline__ float lstm_hc(float a0, float a1, float a2, float a3,
                                         float &c) {
  float A = ex2(-a0);
  float E = ex2(a2);
  float F = ex2(-a1);
  float O = ex2(-a3);
  float igg = (E - 1.f) * fast_rcp((1.f + A) * (1.f + E));   // i * g
  float fg  = fast_rcp(1.f + F);                             // f
  c = fg * c + igg;
  float C = ex2(c * (2.f * L2E));
  return (C - 1.f) * fast_rcp((1.f + O) * (1.f + C));        // o * tanh(c)
}

typedef __attribute__((address_space(3))) unsigned lds_u32_t;
typedef const __attribute__((address_space(1))) unsigned glb_u32_t;
__device__ __forceinline__ void gl_lds16(const void* g, void* l) {
  __builtin_amdgcn_global_load_lds((glb_u32_t*)g, (lds_u32_t*)l, 16, 0, 0);
}

__device__ __forceinline__ f16x8 zf() {
  f16x8 r;
  #pragma unroll
  for (int i = 0; i < 8; ++i) r[i] = (_Float16)0.f;
  return r;
}
__device__ __forceinline__ f16x8 cvt8s(const float* p, float s) {
  float4 a = *(const float4*)p, b = *(const float4*)(p + 4);
  f16x8 r;
  r[0] = (_Float16)(a.x * s); r[1] = (_Float16)(a.y * s);
  r[2] = (_Float16)(a.z * s); r[3] = (_Float16)(a.w * s);
  r[4] = (_Float16)(b.x * s); r[5] = (_Float16)(b.y * s);
  r[6] = (_Float16)(b.z * s); r[7] = (_Float16)(b.w * s);
  return r;
}
__device__ __forceinline__ f16x8 cvt8(const float* p) {
  float4 a = *(const float4*)p, b = *(const float4*)(p + 4);
  f16x8 r;
  r[0] = (_Float16)a.x; r[1] = (_Float16)a.y; r[2] = (_Float16)a.z; r[3] = (_Float16)a.w;
  r[4] = (_Float16)b.x; r[5] = (_Float16)b.y; r[6] = (_Float16)b.z; r[7] = (_Float16)b.w;
  return r;
}
__device__ __forceinline__ f16x8 pk8(float4 a, float4 b) {
  f16x8 r;
  auto p0 = __builtin_amdgcn_cvt_pkrtz(a.x, a.y);
  auto p1 = __builtin_amdgcn_cvt_pkrtz(a.z, a.w);
  auto p2 = __builtin_amdgcn_cvt_pkrtz(b.x, b.y);
  auto p3 = __builtin_amdgcn_cvt_pkrtz(b.z, b.w);
  r[0] = p0[0]; r[1] = p0[1]; r[2] = p1[0]; r[3] = p1[1];
  r[4] = p2[0]; r[5] = p2[1]; r[6] = p3[0]; r[7] = p3[1];
  return r;
}

__global__ __launch_bounds__(NTH, 2) void lstm2_r22_kernel(
    const float* __restrict__ x,
    const float* __restrict__ Wih0, const float* __restrict__ Whh0,
    const float* __restrict__ bih0, const float* __restrict__ bhh0,
    const float* __restrict__ Wih1, const float* __restrict__ Whh1,
    const float* __restrict__ bih1, const float* __restrict__ bhh1,
    const float* __restrict__ W1, const float* __restrict__ b1,
    const float* __restrict__ W2, const float* __restrict__ b2,
    float* __restrict__ out)
{
  // planes: 0,1 = h1 ping-pong; 2,3 = h2 ping-pong (all f16). 118,784 B total.
  __shared__ __align__(16) unsigned short s_h[4][RB * HS];  // 73728 B
  __shared__ __align__(16) float s_x[2][RB * XP];           // 45056 B (tail: hid f32)

  const int tid = threadIdx.x;
  const int l   = tid & 63;
  const int wv  = tid >> 6;        // 0..7
  const bool L0 = (wv < 4);        // wave role: layer 0 vs layer 1
  const int l15 = l & 15;
  const int lg  = l >> 4;
  const int jj  = (wv & 3) * 16 + l15;
  const int k0l = lg * 8;
  const int blk = blockIdx.x;
  const float* xg = x + (size_t)blk * RB * (TT * DD);

  // ---- x-staging: 1408 chunks of 16B (128 rows x 11; chunk 10 of each row = pad) ----
  const int c0 = tid, c1 = 512 + tid, c2 = 1024 + tid;
  const int r0 = c0 / 11, p0 = c0 - r0 * 11;
  const int r1 = c1 / 11, p1 = c1 - r1 * 11;
  const int r2 = c2 / 11, p2 = c2 - r2 * 11;
  const bool v0 = (p0 < 10), v1 = (p1 < 10), v2 = (c2 < 1408) && (p2 < 10);
  const float* xs0 = xg + r0 * (TT * DD) + p0 * 4;
  const float* xs1 = xg + r1 * (TT * DD) + p1 * 4;
  const float* xs2 = xg + r2 * (TT * DD) + p2 * 4;
  const int d0 = wv * 256, d1 = 2048 + wv * 256, d2 = 4096 + wv * 256; // float offs

  // ---- prologue staging: x[0] ----
  if (v0) gl_lds16(xs0, &s_x[0][d0]);
  if (v1) gl_lds16(xs1, &s_x[0][d1]);
  if (v2) gl_lds16(xs2, &s_x[0][d2]);

  // ---- per-role weight fragments (shared registers): 16 frags = 64 VGPR ----
  f16x8 W[16];
  float biasv[4];
  if (L0) {
    #pragma unroll
    for (int g = 0; g < 4; ++g) {
      const float gs = (g == 2) ? 2.f * L2E : L2E;
      int n = g * 64 + jj;
      W[g]      = cvt8s(&Wih0[n * DD + k0l], gs);
      W[4 + g]  = (lg == 0) ? cvt8s(&Wih0[n * DD + 32], gs) : zf();
      W[8 + g]  = cvt8s(&Whh0[n * HH + k0l], gs);
      W[12 + g] = cvt8s(&Whh0[n * HH + 32 + k0l], gs);
      biasv[g] = (bih0[n] + bhh0[n]) * gs;
    }
  } else {
    #pragma unroll
    for (int g = 0; g < 4; ++g) {
      const float gs = (g == 2) ? 2.f * L2E : L2E;
      int n = g * 64 + jj;
      W[g]      = cvt8s(&Wih1[n * HH + k0l], gs);
      W[4 + g]  = cvt8s(&Wih1[n * HH + 32 + k0l], gs);
      W[8 + g]  = cvt8s(&Whh1[n * HH + k0l], gs);
      W[12 + g] = cvt8s(&Whh1[n * HH + 32 + k0l], gs);
      biasv[g] = (bih1[n] + bhh1[n]) * gs;
    }
  }

  float cst[NRT][4];
  #pragma unroll
  for (int rt = 0; rt < NRT; ++rt)
    #pragma unroll
    for (int r = 0; r < 4; ++r) cst[rt][r] = 0.f;

  __syncthreads();   // x[0] staged (vmcnt drained at barrier)

  #pragma unroll 1
  for (int s = 0; s < TT; ++s) {
    if (s) __syncthreads();
    if (s < TT - 1) {          // all threads stage x[s+1]
      float* xd = &s_x[(s + 1) & 1][0];
      const int so = (s + 1) * DD;
      if (v0) gl_lds16(xs0 + so, xd + d0);
      if (v1) gl_lds16(xs1 + so, xd + d1);
      if (v2) gl_lds16(xs2 + so, xd + d2);
    }
    const int p1r = (s - 1) & 1;

    if (L0) {
      // ---- layer 0: h1[s], tiles in PAIRS for cross-tile ILP ----
      const float* xb = &s_x[s & 1][0];
      #pragma unroll
      for (int rp = 0; rp < NRT / 2; ++rp) {
        const int arowA = (2 * rp)     * 16 + l15;
        const int arowB = (2 * rp + 1) * 16 + l15;
        const float* xrA = xb + arowA * XP;
        const float* xrB = xb + arowB * XP;
        f16x8 xhA = pk8(*(const float4*)(xrA + k0l), *(const float4*)(xrA + k0l + 4));
        f16x8 xhB = pk8(*(const float4*)(xrB + k0l), *(const float4*)(xrB + k0l + 4));
        f16x8 xmA = xhA, xmB = xhB;
        if (lg == 0) {
          xmA = pk8(*(const float4*)(xrA + 32), *(const float4*)(xrA + 36));
          xmB = pk8(*(const float4*)(xrB + 32), *(const float4*)(xrB + 36));
        }

        f32x4 accA[4], accB[4];
        #pragma unroll
        for (int g = 0; g < 4; ++g) {
          accA[g] = (f32x4){biasv[g], biasv[g], biasv[g], biasv[g]};
          accB[g] = (f32x4){biasv[g], biasv[g], biasv[g], biasv[g]};
        }

        f16x8 hA0, hA1, hB0, hB1;
        if (s) {
          const unsigned short* hpA = &s_h[p1r][arowA * HS + k0l];
          const unsigned short* hpB = &s_h[p1r][arowB * HS + k0l];
          hA0 = *(const f16x8*)hpA; hA1 = *(const f16x8*)(hpA + 32);
          hB0 = *(const f16x8*)hpB; hB1 = *(const f16x8*)(hpB + 32);
        }
        #pragma unroll
        for (int g = 0; g < 4; ++g) MFMA(accA[g], xhA, W[g]);
        #pragma unroll
        for (int g = 0; g < 4; ++g) MFMA(accB[g], xhB, W[g]);
        #pragma unroll
        for (int g = 0; g < 4; ++g) MFMA(accA[g], xmA, W[4 + g]);
        #pragma unroll
        for (int g = 0; g < 4; ++g) MFMA(accB[g], xmB, W[4 + g]);
        if (s) {
          #pragma unroll
          for (int g = 0; g < 4; ++g) MFMA(accA[g], hA0, W[8 + g]);
          #pragma unroll
          for (int g = 0; g < 4; ++g) MFMA(accB[g], hB0, W[8 + g]);
          #pragma unroll
          for (int g = 0; g < 4; ++g) MFMA(accA[g], hA1, W[12 + g]);
          #pragma unroll
          for (int g = 0; g < 4; ++g) MFMA(accB[g], hB1, W[12 + g]);
        }

        #pragma unroll
        for (int r = 0; r < 4; ++r) {
          float hA = lstm_hc(accA[0][r], accA[1][r], accA[2][r], accA[3][r],
                             cst[2 * rp][r]);
          float hB = lstm_hc(accB[0][r], accB[1][r], accB[2][r], accB[3][r],
                             cst[2 * rp + 1][r]);
          s_h[s & 1][((2 * rp) * 16 + lg * 4 + r) * HS + jj] =
              __builtin_bit_cast(unsigned short, (_Float16)hA);
          s_h[s & 1][((2 * rp + 1) * 16 + lg * 4 + r) * HS + jj] =
              __builtin_bit_cast(unsigned short, (_Float16)hB);
        }
      }
    } else if (s) {
      // ---- layer 1: h2[s-1], tiles in PAIRS ----
      #pragma unroll
      for (int rp = 0; rp < NRT / 2; ++rp) {
        const int arowA = (2 * rp)     * 16 + l15;
        const int arowB = (2 * rp + 1) * 16 + l15;
        const unsigned short* hpA = &s_h[p1r][arowA * HS + k0l];
        const unsigned short* hpB = &s_h[p1r][arowB * HS + k0l];
        f16x8 hA0 = *(const f16x8*)hpA, hA1 = *(const f16x8*)(hpA + 32);
        f16x8 hB0 = *(const f16x8*)hpB, hB1 = *(const f16x8*)(hpB + 32);

        f32x4 accA[4], accB[4];
        #pragma unroll
        for (int g = 0; g < 4; ++g) {
          accA[g] = (f32x4){biasv[g], biasv[g], biasv[g], biasv[g]};
          accB[g] = (f32x4){biasv[g], biasv[g], biasv[g], biasv[g]};
        }

        f16x8 qA0, qA1, qB0, qB1;
        if (s >= 2) {
          const unsigned short* qpA = &s_h[2 + (s & 1)][arowA * HS + k0l];
          const unsigned short* qpB = &s_h[2 + (s & 1)][arowB * HS + k0l];
          qA0 = *(const f16x8*)qpA; qA1 = *(const f16x8*)(qpA + 32);
          qB0 = *(const f16x8*)qpB; qB1 = *(const f16x8*)(qpB + 32);
        }
        #pragma unroll
        for (int g = 0; g < 4; ++g) MFMA(accA[g], hA0, W[g]);
        #pragma unroll
        for (int g = 0; g < 4; ++g) MFMA(accB[g], hB0, W[g]);
        #pragma unroll
        for (int g = 0; g < 4; ++g) MFMA(accA[g], hA1, W[4 + g]);
        #pragma unroll
        for (int g = 0; g < 4; ++g) MFMA(accB[g], hB1, W[4 + g]);
        if (s >= 2) {
          #pragma unroll
          for (int g = 0; g < 4; ++g) MFMA(accA[g], qA0, W[8 + g]);
          #pragma unroll
          for (int g = 0; g < 4; ++g) MFMA(accB[g], qB0, W[8 + g]);
          #pragma unroll
          for (int g = 0; g < 4; ++g) MFMA(accA[g], qA1, W[12 + g]);
          #pragma unroll
          for (int g = 0; g < 4; ++g) MFMA(accB[g], qB1, W[12 + g]);
        }

        #pragma unroll
        for (int r = 0; r < 4; ++r) {
          float hA = lstm_hc(accA[0][r], accA[1][r], accA[2][r], accA[3][r],
                             cst[2 * rp][r]);
          float hB = lstm_hc(accB[0][r], accB[1][r], accB[2][r], accB[3][r],
                             cst[2 * rp + 1][r]);
          s_h[2 + p1r][((2 * rp) * 16 + lg * 4 + r) * HS + jj] =
              __builtin_bit_cast(unsigned short, (_Float16)hA);
          s_h[2 + p1r][((2 * rp + 1) * 16 + lg * 4 + r) * HS + jj] =
              __builtin_bit_cast(unsigned short, (_Float16)hB);
        }
      }
    }
  }

  // ---- final interval: L1 waves compute h2[6] -> f16 plane 1 ----
  __syncthreads();
  if (!L0) {
    #pragma unroll
    for (int rt = 0; rt < NRT; ++rt) {
      const int arow = rt * 16 + l15;
      const unsigned short* hp = &s_h[0][arow * HS + k0l];   // h1[6] (6&1=0)
      f16x8 h1a = *(const f16x8*)hp;
      f16x8 h1b = *(const f16x8*)(hp + 32);
      const unsigned short* qp = &s_h[3][arow * HS + k0l];   // h2[5] (2+(5&1)=3)
      f16x8 q0 = *(const f16x8*)qp;
      f16x8 q1 = *(const f16x8*)(qp + 32);
      f32x4 acc[4];
      #pragma unroll
      for (int g = 0; g < 4; ++g)
        acc[g] = (f32x4){biasv[g], biasv[g], biasv[g], biasv[g]};
      #pragma unroll
      for (int g = 0; g < 4; ++g) MFMA(acc[g], h1a, W[g]);
      #pragma unroll
      for (int g = 0; g < 4; ++g) MFMA(acc[g], h1b, W[4 + g]);
      #pragma unroll
      for (int g = 0; g < 4; ++g) MFMA(acc[g], q0, W[8 + g]);
      #pragma unroll
      for (int g = 0; g < 4; ++g) MFMA(acc[g], q1, W[12 + g]);
      #pragma unroll
      for (int r = 0; r < 4; ++r) {
        float h = lstm_hc(acc[0][r], acc[1][r], acc[2][r], acc[3][r], cst[rt][r]);
        s_h[1][(rt * 16 + lg * 4 + r) * HS + jj] =
            __builtin_bit_cast(unsigned short, (_Float16)h);
      }
    }
  }
  __syncthreads();

  // ---- FC head via MFMA: hid = relu(h2 @ W1^T + b1); wave wv owns row-tile wv ----
  {
    const unsigned short* ap = &s_h[1][(wv * 16 + l15) * HS + k0l];
    f16x8 A0 = *(const f16x8*)ap;
    f16x8 A1 = *(const f16x8*)(ap + 32);
    f16x8 Bf0[2], Bf1[2];
    f32x4 accf[2];
    #pragma unroll
    for (int f = 0; f < 2; ++f) {
      int n = f * 16 + l15;
      Bf0[f] = cvt8(&W1[n * 64 + k0l]);          // global, L2-hot
      Bf1[f] = cvt8(&W1[n * 64 + 32 + k0l]);
      float bb = b1[n];
      accf[f] = (f32x4){bb, bb, bb, bb};
    }
    #pragma unroll
    for (int f = 0; f < 2; ++f) { MFMA(accf[f], A0, Bf0[f]); MFMA(accf[f], A1, Bf1[f]); }
    float* hid = &s_x[0][0];   // [128][36] f32 (x buffers dead)
    #pragma unroll
    for (int f = 0; f < 2; ++f)
      #pragma unroll
      for (int r = 0; r < 4; ++r)
        hid[(wv * 16 + lg * 4 + r) * 36 + f * 16 + l15] = fmaxf(accf[f][r], 0.f);
  }
  __syncthreads();
  if (tid < RB) {
    const float* hid = &s_x[0][0];
    float a = b2[0];
    #pragma unroll
    for (int kq = 0; kq < 8; ++kq) {
      float4 hv = *(const float4*)&hid[tid * 36 + kq * 4];
      float4 wv4 = *(const float4*)&W2[kq * 4];
      a += hv.x * wv4.x + hv.y * wv4.y + hv.z * wv4.z + hv.w * wv4.w;
    }
    out[blk * RB + tid] = a;
  }
}

extern "C" void kernel_launch(void* const* d_in, const int* in_sizes, int n_in,
                              void* d_out, int out_size, void* d_ws, size_t ws_size,
                              hipStream_t stream) {
  const float* x    = (const float*)d_in[0];
  const float* Wih0 = (const float*)d_in[1];
  const float* Whh0 = (const float*)d_in[2];
  const float* bih0 = (const float*)d_in[3];
  const float* bhh0 = (const float*)d_in[4];
  const float* Wih1 = (const float*)d_in[5];
  const float* Whh1 = (const float*)d_in[6];
  const float* bih1 = (const float*)d_in[7];
  const float* bhh1 = (const float*)d_in[8];
  const float* W1   = (const float*)d_in[9];
  const float* b1   = (const float*)d_in[10];
  const float* W2   = (const float*)d_in[11];
  const float* b2   = (const float*)d_in[12];
  float* out = (float*)d_out;

  const int Btot = in_sizes[0] / (TT * DD);   // 32768
  dim3 grid(Btot / RB), block(NTH);           // 256 blocks = exactly 1 per CU
  lstm2_r22_kernel<<<grid, block, 0, stream>>>(
      x, Wih0, Whh0, bih0, bhh0, Wih1, Whh1, bih1, bhh1, W1, b1, W2, b2, out);
}